// Round 12
// baseline (179.483 us; speedup 1.0000x reference)
//
#include <hip/hip_runtime.h>
#include <hip/hip_bf16.h>

#define B_    8
#define N_    2048
#define FIN_  256
#define FOUT_ 128
#define NROWS (B_*N_)
#define OSZ   ((size_t)NROWS * FOUT_)
#define L2E   1.44269504f

typedef __attribute__((ext_vector_type(8))) short short8;
typedef __attribute__((ext_vector_type(4))) float f32x4;

__device__ __forceinline__ float bf2f(unsigned short u) {
  return __uint_as_float(((unsigned int)u) << 16);
}
__device__ __forceinline__ unsigned short f2bf(float f) {
  unsigned int u = __float_as_uint(f);
  u += 0x7FFFu + ((u >> 16) & 1u);   // RNE
  return (unsigned short)(u >> 16);
}
__device__ __forceinline__ float ldin(const void* p, size_t idx, int isbf) {
  if (isbf) return bf2f(((const unsigned short*)p)[idx]);
  return ((const float*)p)[idx];
}
__device__ __forceinline__ unsigned pk2bf(float a, float b) {
  return (unsigned)f2bf(a) | ((unsigned)f2bf(b) << 16);   // low = a (RNE)
}
// monotone float<->uint encoding for atomicMax float-max (all finite enc > 0)
__device__ __forceinline__ unsigned encf(float f) {
  unsigned u = __float_as_uint(f);
  return (u & 0x80000000u) ? ~u : (u | 0x80000000u);
}
__device__ __forceinline__ float decf(unsigned k) {
  return (k & 0x80000000u) ? __uint_as_float(k ^ 0x80000000u) : __uint_as_float(~k);
}
// per-block dtype self-detect (deterministic across blocks)
__device__ __forceinline__ int detect_bf(const void* x, int* cnt) {
  const unsigned short* u = (const unsigned short*)x;
  int c = 0;
  for (int i = threadIdx.x; i < 8192; i += 256) {
    unsigned short v = u[i];
    int e = (v >> 7) & 0xFF;
    if ((e >= 110 && e <= 145) || (v & 0x7FFF) == 0) c++;
  }
  cnt[threadIdx.x] = c;
  __syncthreads();
  for (int s = 128; s > 0; s >>= 1) {
    if (threadIdx.x < s) cnt[threadIdx.x] += cnt[threadIdx.x + s];
    __syncthreads();
  }
  return cnt[0] > 7373;   // 0.9 * 8192
}

// ---------- kernel 0: self-detect; blocks 0..127: WT; block 128: wa, flag,
//            MdstE init ----------
__global__ __launch_bounds__(256)
void k_prep(const void* __restrict__ x, const void* __restrict__ W,
            const void* __restrict__ a,
            unsigned short* __restrict__ WT, float* __restrict__ wa,
            int* __restrict__ flag, unsigned* __restrict__ MdstE) {
  __shared__ int cnt[256];
  const int isbf = detect_bf(x, cnt);
  if (blockIdx.x < 128) {
    int f = blockIdx.x, k = threadIdx.x;
    WT[f * 256 + k] = f2bf(ldin(W, (size_t)k * 128 + f, isbf));
  } else {
    __shared__ float as_s[256];
    int k = threadIdx.x;
    as_s[k] = ldin(a, k, isbf);
    __syncthreads();
    float s = 0.f, d = 0.f;
    for (int f = 0; f < 128; f++) {
      float w = ldin(W, (size_t)k * 128 + f, isbf);
      s += w * as_s[f];
      d += w * as_s[128 + f];
    }
    wa[k] = s;
    wa[256 + k] = d;
    if (k == 0) *flag = isbf;
    if (k < 8) MdstE[k * 32] = 0u;     // 0 < enc(f) for all finite f
  }
}

// ---------- kernel 1: h = x@W bf16 MFMA -> hT; fused fsrc/fdst = x@wa;
//            fused per-batch fdst max via 1 padded atomic per block ----------
__global__ __launch_bounds__(256)
void k_h(const void* __restrict__ x, const unsigned short* __restrict__ WT,
         const float* __restrict__ wa, const int* __restrict__ flag,
         unsigned short* __restrict__ hT, float* __restrict__ fsrc,
         float* __restrict__ fdst, unsigned* __restrict__ MdstE) {
  __shared__ __align__(16) unsigned short xs[32][264];
  __shared__ float wa_s[512];
  __shared__ float mxs[8];
  const int isbf = *flag;
  const int t    = threadIdx.x;
  const int row0 = blockIdx.x * 32;

  wa_s[t] = wa[t];
  wa_s[256 + t] = wa[256 + t];
  __syncthreads();

  const int c = t & 31;
  float sp[4], dp[4];
  if (isbf) {
    const unsigned short* xu = (const unsigned short*)x;
#pragma unroll
    for (int u = 0; u < 4; u++) {
      int r = u * 8 + (t >> 5);
      short8 sh = *(const short8*)&xu[(size_t)(row0 + r) * FIN_ + c * 8];
      *(short8*)&xs[r][c * 8] = sh;
      float s = 0.f, d = 0.f;
#pragma unroll
      for (int e = 0; e < 8; e++) {
        float xv = bf2f((unsigned short)sh[e]);
        s += xv * wa_s[c * 8 + e];
        d += xv * wa_s[256 + c * 8 + e];
      }
      sp[u] = s; dp[u] = d;
    }
  } else {
    const float* xf = (const float*)x;
#pragma unroll
    for (int u = 0; u < 4; u++) {
      int r = u * 8 + (t >> 5);
      float4 v0 = *(const float4*)&xf[(size_t)(row0 + r) * FIN_ + c * 8];
      float4 v1 = *(const float4*)&xf[(size_t)(row0 + r) * FIN_ + c * 8 + 4];
      float vv[8] = {v0.x, v0.y, v0.z, v0.w, v1.x, v1.y, v1.z, v1.w};
      short8 sh;
      float s = 0.f, d = 0.f;
#pragma unroll
      for (int e = 0; e < 8; e++) {
        sh[e] = (short)f2bf(vv[e]);
        s += vv[e] * wa_s[c * 8 + e];
        d += vv[e] * wa_s[256 + c * 8 + e];
      }
      *(short8*)&xs[r][c * 8] = sh;
      sp[u] = s; dp[u] = d;
    }
  }
#pragma unroll
  for (int off = 16; off >= 1; off >>= 1) {
#pragma unroll
    for (int u = 0; u < 4; u++) {
      sp[u] += __shfl_xor(sp[u], off, 64);
      dp[u] += __shfl_xor(dp[u], off, 64);
    }
  }
  if (c == 0) {
    float lm = -1e30f;
#pragma unroll
    for (int u = 0; u < 4; u++) {
      int r = u * 8 + (t >> 5);
      fsrc[row0 + r] = sp[u];
      fdst[row0 + r] = dp[u];
      lm = fmaxf(lm, dp[u]);
    }
    mxs[t >> 5] = lm;
  }
  __syncthreads();
  if (t == 0) {
    float m8 = mxs[0];
#pragma unroll
    for (int i = 1; i < 8; i++) m8 = fmaxf(m8, mxs[i]);
    atomicMax(&MdstE[(row0 >> 11) * 32], encf(m8));   // 64 atomics/line, padded
  }

  const int lane = t & 63, w = t >> 6;
  const int m = lane & 15, quad = lane >> 4;
  const int slab = w >> 1, fh = w & 1;

  f32x4 acc[4];
#pragma unroll
  for (int i = 0; i < 4; i++) acc[i] = (f32x4){0.f, 0.f, 0.f, 0.f};

#pragma unroll
  for (int ks = 0; ks < 8; ks++) {
    short8 ah = *(const short8*)&xs[slab * 16 + m][ks * 32 + quad * 8];
#pragma unroll
    for (int ft = 0; ft < 4; ft++) {
      int f = fh * 64 + ft * 16 + m;
      short8 bh = *(const short8*)&WT[(size_t)f * 256 + ks * 32 + quad * 8];
      acc[ft] = __builtin_amdgcn_mfma_f32_16x16x32_bf16(ah, bh, acc[ft], 0, 0, 0);
    }
  }

  size_t n0 = (size_t)blockIdx.x * 2 + slab;
  unsigned short* hblk = hT + n0 * (FOUT_ * 16);
#pragma unroll
  for (int ft = 0; ft < 4; ft++) {
    int f = fh * 64 + ft * 16 + m;
    *(uint2*)&hblk[f * 16 + quad * 4] = make_uint2(
        pk2bf(acc[ft][0], acc[ft][1]), pk2bf(acc[ft][2], acc[ft][3]));
  }
}

// ---------- kernel 2: j-split gated attention -> fp32 partials --------------
// Grid = B*128*2: b = bid>>8, q0 = ((bid>>1)&127)*16, half = bid&1.
// Each block: 16 queries x 1024 j (8 tiles of 128). Verified dataflow:
// p -> LDS phi (packed bf16) -> ds_read A-frag -> MFMA; B-frags in one
// register set reloaded after each tile's MFMA (covered by next logit phase).
__global__ __launch_bounds__(256, 6)
void k_attn(const unsigned short* __restrict__ hT, const void* __restrict__ coord,
            const float* __restrict__ fsrc, const float* __restrict__ fdst,
            const unsigned* __restrict__ MdstE, const int* __restrict__ flag,
            float* __restrict__ Opart, float* __restrict__ lpart) {
  const int isbf = *flag;
  const int tid  = threadIdx.x;
  const int b    = blockIdx.x >> 8;
  const int q0   = ((blockIdx.x >> 1) & 127) * 16;
  const int half = blockIdx.x & 1;
  const int jo   = half * 1024;                   // this block's j-offset

  __shared__ __align__(16) float4 cjs[2][128];    // (cx,cy,cz,fdst) 4 KB
  __shared__ __align__(16) unsigned short phi[2][16][136];
  __shared__ float lred[16][16];                  // [jseg][qA]

  const int qA   = tid & 15;
  const int jseg = tid >> 4;                      // 0..15, 8 j's per 128-tile
  const size_t qglb = (size_t)b * N_ + q0 + qA;
  const float cq0 = ldin(coord, qglb * 3 + 0, isbf);
  const float cq1 = ldin(coord, qglb * 3 + 1, isbf);
  const float cq2 = ldin(coord, qglb * 3 + 2, isbf);
  const float fsq = fsrc[qglb];
  const float Bq  = fmaxf(0.f, fsq + decf(MdstE[b * 32]));
  const float BqL = Bq * L2E;
  float lacc = 0.f;

  const int lane = tid & 63, w = tid >> 6;
  const int m = lane & 15, quad = lane >> 4;
  f32x4 acc[2];
  acc[0] = (f32x4){0.f, 0.f, 0.f, 0.f};
  acc[1] = (f32x4){0.f, 0.f, 0.f, 0.f};

  const unsigned short* hTb = hT + (size_t)b * (N_ * FOUT_);
  const int colA = (w * 2 + 0) * 16 + m;
  const int colB = (w * 2 + 1) * 16 + m;
  const int co   = (quad & 1) * 8;
  const int chq  = quad >> 1;
  const int chb  = half * 64;                     // chunk base for this half

  // prologue: stage tile-0 coords + load tile-0 B-fragments
  if (tid < 128) {
    size_t jg = (size_t)b * N_ + jo + tid;
    cjs[0][tid] = make_float4(ldin(coord, jg * 3 + 0, isbf), ldin(coord, jg * 3 + 1, isbf),
                              ldin(coord, jg * 3 + 2, isbf), fdst[jg]);
  }
  short8 bcur[8];
#pragma unroll
  for (int ks = 0; ks < 4; ks++) {
    size_t base = (size_t)(chb + ks * 2 + chq) * (FOUT_ * 16) + co;
    bcur[ks * 2 + 0] = *(const short8*)&hTb[base + colA * 16];
    bcur[ks * 2 + 1] = *(const short8*)&hTb[base + colB * 16];
  }
  __syncthreads();

  for (int t = 0; t < 8; t++) {
    const int buf = t & 1;

    // stage NEXT tile's coords (write nbuf; prior reads of nbuf ended at the
    // previous barrier -- one-barrier ladder, verified r9/r10)
    if (t < 7 && tid < 128) {
      size_t jg = (size_t)b * N_ + jo + (t + 1) * 128 + tid;
      cjs[buf ^ 1][tid] = make_float4(ldin(coord, jg * 3 + 0, isbf), ldin(coord, jg * 3 + 1, isbf),
                                      ldin(coord, jg * 3 + 2, isbf), fdst[jg]);
    }

    // ---- logits: 8 j's -> packed bf16 -> one uint4 LDS store ----
    unsigned pk[4];
#pragma unroll
    for (int jp = 0; jp < 4; jp++) {
      float pv[2];
#pragma unroll
      for (int h = 0; h < 2; h++) {
        float4 cj = cjs[buf][jseg * 8 + jp * 2 + h];
        float dx = cq0 - cj.x, dy = cq1 - cj.y, dz = cq2 - cj.z;
        float d2 = dx * dx + dy * dy + dz * dz;
        float loc = exp2f(d2 * (-0.1f * L2E));
        float e = fsq + cj.w;
        e = fmaxf(e, 0.2f * e);                       // leaky relu
        float p = (loc > 0.01f) ? exp2f(fmaf(e * L2E, loc, -BqL)) : 0.f;
        pv[h] = p;
        lacc += p;
      }
      pk[jp] = pk2bf(pv[0], pv[1]);
    }
    *(uint4*)&phi[buf][qA][jseg * 8] = make_uint4(pk[0], pk[1], pk[2], pk[3]);
    __syncthreads();   // one barrier per 128-j tile

    // ---- PV MFMA: 4 k-steps of 32, 2 f-tiles ----
#pragma unroll
    for (int ks = 0; ks < 4; ks++) {
      short8 ah = *(const short8*)&phi[buf][m][ks * 32 + quad * 8];
      acc[0] = __builtin_amdgcn_mfma_f32_16x16x32_bf16(ah, bcur[ks * 2 + 0], acc[0], 0, 0, 0);
      acc[1] = __builtin_amdgcn_mfma_f32_16x16x32_bf16(ah, bcur[ks * 2 + 1], acc[1], 0, 0, 0);
    }
    // reload B-fragments for tile t+1 (latency covered by next logit phase)
    if (t < 7) {
      const int jcb = chb + (t + 1) * 8;
#pragma unroll
      for (int ks = 0; ks < 4; ks++) {
        size_t base = (size_t)(jcb + ks * 2 + chq) * (FOUT_ * 16) + co;
        bcur[ks * 2 + 0] = *(const short8*)&hTb[base + colA * 16];
        bcur[ks * 2 + 1] = *(const short8*)&hTb[base + colB * 16];
      }
    }
  }

  // ---- partial denominator + partial O to workspace ----
  lred[jseg][qA] = lacc;
  __syncthreads();
  if (tid < 16) {
    float s = 0.f;
#pragma unroll
    for (int k = 0; k < 16; k++) s += lred[k][tid];
    lpart[(size_t)half * NROWS + (size_t)b * N_ + q0 + tid] = s;
  }
  float* Oh = Opart + (size_t)half * OSZ;
#pragma unroll
  for (int f2 = 0; f2 < 2; f2++) {
    int f = (w * 2 + f2) * 16 + m;
#pragma unroll
    for (int r = 0; r < 4; r++) {
      int q = quad * 4 + r;
      Oh[((size_t)b * N_ + q0 + q) * FOUT_ + f] = acc[f2][r];
    }
  }
}

// ---------- kernel 3: combine halves, normalize, elu, store ----------
__global__ __launch_bounds__(256)
void k_comb(const float* __restrict__ Opart, const float* __restrict__ lpart,
            const int* __restrict__ flag, void* __restrict__ out) {
  const int isbf = *flag;
  const int tid = threadIdx.x;
  const size_t row = (size_t)blockIdx.x * 8 + (tid >> 5);
  const int f0 = (tid & 31) * 4;
  float l = lpart[row] + lpart[NROWS + row];
  float inv = 1.0f / fmaxf(l, 1e-30f);
  float4 o0 = *(const float4*)&Opart[row * FOUT_ + f0];
  float4 o1 = *(const float4*)&Opart[OSZ + row * FOUT_ + f0];
  float4 v;
  v.x = (o0.x + o1.x) * inv; v.y = (o0.y + o1.y) * inv;
  v.z = (o0.z + o1.z) * inv; v.w = (o0.w + o1.w) * inv;
  v.x = (v.x > 0.f) ? v.x : expm1f(v.x);
  v.y = (v.y > 0.f) ? v.y : expm1f(v.y);
  v.z = (v.z > 0.f) ? v.z : expm1f(v.z);
  v.w = (v.w > 0.f) ? v.w : expm1f(v.w);
  if (isbf) {
    uint2 u = make_uint2(pk2bf(v.x, v.y), pk2bf(v.z, v.w));
    *(uint2*)((unsigned short*)out + row * FOUT_ + f0) = u;
  } else {
    *(float4*)((float*)out + row * FOUT_ + f0) = v;
  }
}

extern "C" void kernel_launch(void* const* d_in, const int* in_sizes, int n_in,
                              void* d_out, int out_size, void* d_ws, size_t ws_size,
                              hipStream_t stream) {
  const void* x     = d_in[0];
  const void* coord = d_in[1];
  const void* W     = d_in[2];
  const void* a     = d_in[3];

  // ws: [512-float header: flag@0, MdstE @ uint 64 (stride 32)]
  //     [hT][WT][wa][fsrc][fdst][lpart x2][Opart x2]
  int*            flag  = (int*)d_ws;
  unsigned*       MdstE = (unsigned*)d_ws + 64;
  unsigned short* hT    = (unsigned short*)((float*)d_ws + 512);
  unsigned short* WT    = hT + (size_t)NROWS * FOUT_;
  float*          wa    = (float*)(WT + 128 * 256);
  float*          fsrc  = wa + 512;
  float*          fdst  = fsrc + NROWS;
  float*          lpart = fdst + NROWS;
  float*          Opart = lpart + 2 * NROWS;

  k_prep<<<129, 256, 0, stream>>>(x, W, a, WT, wa, flag, MdstE);
  k_h   <<<NROWS / 32, 256, 0, stream>>>(x, WT, wa, flag, hT, fsrc, fdst, MdstE);
  k_attn<<<B_ * 128 * 2, 256, 0, stream>>>(hT, coord, fsrc, fdst, MdstE, flag, Opart, lpart);
  k_comb<<<NROWS / 8, 256, 0, stream>>>(Opart, lpart, flag, d_out);
}

// Round 13
// 145.144 us; speedup vs baseline: 1.2366x; 1.2366x over previous
//
#include <hip/hip_runtime.h>
#include <hip/hip_bf16.h>

#define B_    8
#define N_    2048
#define FIN_  256
#define FOUT_ 128
#define NROWS (B_*N_)
#define L2E   1.44269504f

typedef __attribute__((ext_vector_type(8))) short short8;
typedef __attribute__((ext_vector_type(4))) float f32x4;

__device__ __forceinline__ float bf2f(unsigned short u) {
  return __uint_as_float(((unsigned int)u) << 16);
}
__device__ __forceinline__ unsigned short f2bf(float f) {
  unsigned int u = __float_as_uint(f);
  u += 0x7FFFu + ((u >> 16) & 1u);   // RNE
  return (unsigned short)(u >> 16);
}
__device__ __forceinline__ float ldin(const void* p, size_t idx, int isbf) {
  if (isbf) return bf2f(((const unsigned short*)p)[idx]);
  return ((const float*)p)[idx];
}
__device__ __forceinline__ unsigned pk2bf(float a, float b) {
  return (unsigned)f2bf(a) | ((unsigned)f2bf(b) << 16);   // low = a (RNE)
}
// monotone float<->uint encoding for atomicMax float-max (all finite enc > 0)
__device__ __forceinline__ unsigned encf(float f) {
  unsigned u = __float_as_uint(f);
  return (u & 0x80000000u) ? ~u : (u | 0x80000000u);
}
__device__ __forceinline__ float decf(unsigned k) {
  return (k & 0x80000000u) ? __uint_as_float(k ^ 0x80000000u) : __uint_as_float(~k);
}
// per-block dtype self-detect (deterministic across blocks)
__device__ __forceinline__ int detect_bf(const void* x, int* cnt) {
  const unsigned short* u = (const unsigned short*)x;
  int c = 0;
  for (int i = threadIdx.x; i < 8192; i += 256) {
    unsigned short v = u[i];
    int e = (v >> 7) & 0xFF;
    if ((e >= 110 && e <= 145) || (v & 0x7FFF) == 0) c++;
  }
  cnt[threadIdx.x] = c;
  __syncthreads();
  for (int s = 128; s > 0; s >>= 1) {
    if (threadIdx.x < s) cnt[threadIdx.x] += cnt[threadIdx.x + s];
    __syncthreads();
  }
  return cnt[0] > 7373;   // 0.9 * 8192
}

// ---------- kernel 0: self-detect; blocks 0..127: WT; block 128: wa, flag,
//            MdstE init ----------
__global__ __launch_bounds__(256)
void k_prep(const void* __restrict__ x, const void* __restrict__ W,
            const void* __restrict__ a,
            unsigned short* __restrict__ WT, float* __restrict__ wa,
            int* __restrict__ flag, unsigned* __restrict__ MdstE) {
  __shared__ int cnt[256];
  const int isbf = detect_bf(x, cnt);
  if (blockIdx.x < 128) {
    int f = blockIdx.x, k = threadIdx.x;
    WT[f * 256 + k] = f2bf(ldin(W, (size_t)k * 128 + f, isbf));
  } else {
    __shared__ float as_s[256];
    int k = threadIdx.x;
    as_s[k] = ldin(a, k, isbf);
    __syncthreads();
    float s = 0.f, d = 0.f;
    for (int f = 0; f < 128; f++) {
      float w = ldin(W, (size_t)k * 128 + f, isbf);
      s += w * as_s[f];
      d += w * as_s[128 + f];
    }
    wa[k] = s;
    wa[256 + k] = d;
    if (k == 0) *flag = isbf;
    if (k < 8) MdstE[k * 32] = 0u;     // 0 < enc(f) for all finite f
  }
}

// ---------- kernel 1: h = x@W bf16 MFMA -> hT; fused fsrc/fdst = x@wa;
//            fused per-batch fdst max via 1 padded atomic per block ----------
__global__ __launch_bounds__(256)
void k_h(const void* __restrict__ x, const unsigned short* __restrict__ WT,
         const float* __restrict__ wa, const int* __restrict__ flag,
         unsigned short* __restrict__ hT, float* __restrict__ fsrc,
         float* __restrict__ fdst, unsigned* __restrict__ MdstE) {
  __shared__ __align__(16) unsigned short xs[32][264];
  __shared__ float wa_s[512];
  __shared__ float mxs[8];
  const int isbf = *flag;
  const int t    = threadIdx.x;
  const int row0 = blockIdx.x * 32;

  wa_s[t] = wa[t];
  wa_s[256 + t] = wa[256 + t];
  __syncthreads();

  const int c = t & 31;
  float sp[4], dp[4];
  if (isbf) {
    const unsigned short* xu = (const unsigned short*)x;
#pragma unroll
    for (int u = 0; u < 4; u++) {
      int r = u * 8 + (t >> 5);
      short8 sh = *(const short8*)&xu[(size_t)(row0 + r) * FIN_ + c * 8];
      *(short8*)&xs[r][c * 8] = sh;
      float s = 0.f, d = 0.f;
#pragma unroll
      for (int e = 0; e < 8; e++) {
        float xv = bf2f((unsigned short)sh[e]);
        s += xv * wa_s[c * 8 + e];
        d += xv * wa_s[256 + c * 8 + e];
      }
      sp[u] = s; dp[u] = d;
    }
  } else {
    const float* xf = (const float*)x;
#pragma unroll
    for (int u = 0; u < 4; u++) {
      int r = u * 8 + (t >> 5);
      float4 v0 = *(const float4*)&xf[(size_t)(row0 + r) * FIN_ + c * 8];
      float4 v1 = *(const float4*)&xf[(size_t)(row0 + r) * FIN_ + c * 8 + 4];
      float vv[8] = {v0.x, v0.y, v0.z, v0.w, v1.x, v1.y, v1.z, v1.w};
      short8 sh;
      float s = 0.f, d = 0.f;
#pragma unroll
      for (int e = 0; e < 8; e++) {
        sh[e] = (short)f2bf(vv[e]);
        s += vv[e] * wa_s[c * 8 + e];
        d += vv[e] * wa_s[256 + c * 8 + e];
      }
      *(short8*)&xs[r][c * 8] = sh;
      sp[u] = s; dp[u] = d;
    }
  }
#pragma unroll
  for (int off = 16; off >= 1; off >>= 1) {
#pragma unroll
    for (int u = 0; u < 4; u++) {
      sp[u] += __shfl_xor(sp[u], off, 64);
      dp[u] += __shfl_xor(dp[u], off, 64);
    }
  }
  if (c == 0) {
    float lm = -1e30f;
#pragma unroll
    for (int u = 0; u < 4; u++) {
      int r = u * 8 + (t >> 5);
      fsrc[row0 + r] = sp[u];
      fdst[row0 + r] = dp[u];
      lm = fmaxf(lm, dp[u]);
    }
    mxs[t >> 5] = lm;
  }
  __syncthreads();
  if (t == 0) {
    float m8 = mxs[0];
#pragma unroll
    for (int i = 1; i < 8; i++) m8 = fmaxf(m8, mxs[i]);
    atomicMax(&MdstE[(row0 >> 11) * 32], encf(m8));   // 64 atomics/line, padded
  }

  const int lane = t & 63, w = t >> 6;
  const int m = lane & 15, quad = lane >> 4;
  const int slab = w >> 1, fh = w & 1;

  f32x4 acc[4];
#pragma unroll
  for (int i = 0; i < 4; i++) acc[i] = (f32x4){0.f, 0.f, 0.f, 0.f};

#pragma unroll
  for (int ks = 0; ks < 8; ks++) {
    short8 ah = *(const short8*)&xs[slab * 16 + m][ks * 32 + quad * 8];
#pragma unroll
    for (int ft = 0; ft < 4; ft++) {
      int f = fh * 64 + ft * 16 + m;
      short8 bh = *(const short8*)&WT[(size_t)f * 256 + ks * 32 + quad * 8];
      acc[ft] = __builtin_amdgcn_mfma_f32_16x16x32_bf16(ah, bh, acc[ft], 0, 0, 0);
    }
  }

  size_t n0 = (size_t)blockIdx.x * 2 + slab;
  unsigned short* hblk = hT + n0 * (FOUT_ * 16);
#pragma unroll
  for (int ft = 0; ft < 4; ft++) {
    int f = fh * 64 + ft * 16 + m;
    *(uint2*)&hblk[f * 16 + quad * 4] = make_uint2(
        pk2bf(acc[ft][0], acc[ft][1]), pk2bf(acc[ft][2], acc[ft][3]));
  }
}

// ---------- kernel 2: single-pass gated attention, full j-range -------------
// Grid = B*(N/16) = 1024 blocks, 256 threads. Round-10 verified structure
// (cjs[1024] half-staged, restage at t==8; p -> LDS phi packed bf16 ->
// ds_read A-frag -> MFMA) with round-12's B-fragment handling: ONE register
// set, reloaded right after each tile's MFMA, consumed after the next
// logit-phase + barrier (VGPR ~40 -- the dual-set prefetch was compiler-
// defeated at VGPR 64 in r10). Output written directly (no fp32 partial
// round-trip: r12 showed 7x HBM write amplification on that path).
__global__ __launch_bounds__(256, 6)
void k_attn(const unsigned short* __restrict__ hT, const void* __restrict__ coord,
            const float* __restrict__ fsrc, const float* __restrict__ fdst,
            const unsigned* __restrict__ MdstE, const int* __restrict__ flag,
            void* __restrict__ out) {
  const int isbf = *flag;
  const int tid = threadIdx.x;
  const int b   = blockIdx.x >> 7;
  const int q0  = (blockIdx.x & 127) * 16;

  __shared__ __align__(16) float4 cjs[1024];            // 16 KB (cx,cy,cz,fdst)
  __shared__ __align__(16) unsigned short phi[2][16][136];
  __shared__ float lred[16][16];                        // [jseg][qA]

  const int qA   = tid & 15;
  const int jseg = tid >> 4;                            // 0..15, 8 j's each
  const size_t qglb = (size_t)b * N_ + q0 + qA;
  const float cq0 = ldin(coord, qglb * 3 + 0, isbf);
  const float cq1 = ldin(coord, qglb * 3 + 1, isbf);
  const float cq2 = ldin(coord, qglb * 3 + 2, isbf);
  const float fsq = fsrc[qglb];
  const float Bq  = fmaxf(0.f, fsq + decf(MdstE[b * 32]));
  const float BqL = Bq * L2E;
  float lacc = 0.f;

  const int lane = tid & 63, w = tid >> 6;
  const int m = lane & 15, quad = lane >> 4;
  f32x4 acc[2];
  acc[0] = (f32x4){0.f, 0.f, 0.f, 0.f};
  acc[1] = (f32x4){0.f, 0.f, 0.f, 0.f};

  const unsigned short* hTb = hT + (size_t)b * (N_ * FOUT_);
  const int colA = (w * 2 + 0) * 16 + m;
  const int colB = (w * 2 + 1) * 16 + m;
  const int co   = (quad & 1) * 8;
  const int chq  = quad >> 1;

  // stage half 0 (j in [0,1024)) with all 256 threads
  for (int r = tid; r < 1024; r += 256) {
    size_t jg = (size_t)b * N_ + r;
    cjs[r] = make_float4(ldin(coord, jg * 3 + 0, isbf), ldin(coord, jg * 3 + 1, isbf),
                         ldin(coord, jg * 3 + 2, isbf), fdst[jg]);
  }
  // tile-0 B-fragments
  short8 bcur[8];
#pragma unroll
  for (int ks = 0; ks < 4; ks++) {
    size_t base = (size_t)(ks * 2 + chq) * (FOUT_ * 16) + co;
    bcur[ks * 2 + 0] = *(const short8*)&hTb[base + colA * 16];
    bcur[ks * 2 + 1] = *(const short8*)&hTb[base + colB * 16];
  }
  __syncthreads();

  for (int t = 0; t < 16; t++) {
    if (t == 8) {
      // all waves past barrier_7 (done reading half 0); restage half 1
      for (int r = tid; r < 1024; r += 256) {
        size_t jg = (size_t)b * N_ + 1024 + r;
        cjs[r] = make_float4(ldin(coord, jg * 3 + 0, isbf), ldin(coord, jg * 3 + 1, isbf),
                             ldin(coord, jg * 3 + 2, isbf), fdst[jg]);
      }
      __syncthreads();
    }
    const int buf = t & 1;

    // ---- logits: 8 j's -> packed bf16 -> one uint4 LDS store ----
    const int jbase = (t & 7) * 128 + jseg * 8;
    unsigned pk[4];
#pragma unroll
    for (int jp = 0; jp < 4; jp++) {
      float pv[2];
#pragma unroll
      for (int h = 0; h < 2; h++) {
        float4 cj = cjs[jbase + jp * 2 + h];
        float dx = cq0 - cj.x, dy = cq1 - cj.y, dz = cq2 - cj.z;
        float d2 = dx * dx + dy * dy + dz * dz;
        float loc = exp2f(d2 * (-0.1f * L2E));
        float e = fsq + cj.w;
        e = fmaxf(e, 0.2f * e);                       // leaky relu
        float p = (loc > 0.01f) ? exp2f(fmaf(e * L2E, loc, -BqL)) : 0.f;
        pv[h] = p;
        lacc += p;
      }
      pk[jp] = pk2bf(pv[0], pv[1]);
    }
    *(uint4*)&phi[buf][qA][jseg * 8] = make_uint4(pk[0], pk[1], pk[2], pk[3]);
    __syncthreads();   // one barrier per 128-j tile

    // ---- PV MFMA: 4 k-steps of 32, 2 f-tiles ----
#pragma unroll
    for (int ks = 0; ks < 4; ks++) {
      short8 ah = *(const short8*)&phi[buf][m][ks * 32 + quad * 8];
      acc[0] = __builtin_amdgcn_mfma_f32_16x16x32_bf16(ah, bcur[ks * 2 + 0], acc[0], 0, 0, 0);
      acc[1] = __builtin_amdgcn_mfma_f32_16x16x32_bf16(ah, bcur[ks * 2 + 1], acc[1], 0, 0, 0);
    }
    // reload B-fragments for tile t+1 (covered by next logit phase + barrier)
    if (t < 15) {
      const int jcb = (t + 1) * 8;
#pragma unroll
      for (int ks = 0; ks < 4; ks++) {
        size_t base = (size_t)(jcb + ks * 2 + chq) * (FOUT_ * 16) + co;
        bcur[ks * 2 + 0] = *(const short8*)&hTb[base + colA * 16];
        bcur[ks * 2 + 1] = *(const short8*)&hTb[base + colB * 16];
      }
    }
  }

  // ---- denominator ----
  lred[jseg][qA] = lacc;
  __syncthreads();
  float dinv[4];
#pragma unroll
  for (int r = 0; r < 4; r++) {
    int q = quad * 4 + r;
    float s = 0.f;
#pragma unroll
    for (int k = 0; k < 16; k++) s += lred[k][q];
    dinv[r] = 1.0f / fmaxf(s, 1e-30f);
  }

  // ---- normalize, elu, store (D: row q = quad*4+r, col f) ----
#pragma unroll
  for (int f2 = 0; f2 < 2; f2++) {
    int f = (w * 2 + f2) * 16 + m;
#pragma unroll
    for (int r = 0; r < 4; r++) {
      int q = quad * 4 + r;
      float v = acc[f2][r] * dinv[r];
      v = (v > 0.f) ? v : expm1f(v);
      size_t oidx = ((size_t)(b * N_ + q0 + q)) * FOUT_ + f;
      if (isbf) ((unsigned short*)out)[oidx] = f2bf(v);
      else      ((float*)out)[oidx] = v;
    }
  }
}

extern "C" void kernel_launch(void* const* d_in, const int* in_sizes, int n_in,
                              void* d_out, int out_size, void* d_ws, size_t ws_size,
                              hipStream_t stream) {
  const void* x     = d_in[0];
  const void* coord = d_in[1];
  const void* W     = d_in[2];
  const void* a     = d_in[3];

  // ws: [512-float header: flag@0, MdstE @ uint 64 (stride 32)]
  //     [hT][WT][wa][fsrc][fdst]
  int*            flag  = (int*)d_ws;
  unsigned*       MdstE = (unsigned*)d_ws + 64;
  unsigned short* hT    = (unsigned short*)((float*)d_ws + 512);
  unsigned short* WT    = hT + (size_t)NROWS * FOUT_;
  float*          wa    = (float*)(WT + 128 * 256);
  float*          fsrc  = wa + 512;
  float*          fdst  = fsrc + NROWS;

  k_prep<<<129, 256, 0, stream>>>(x, W, a, WT, wa, flag, MdstE);
  k_h   <<<NROWS / 32, 256, 0, stream>>>(x, WT, wa, flag, hT, fsrc, fdst, MdstE);
  k_attn<<<B_ * (N_ / 16), 256, 0, stream>>>(hT, coord, fsrc, fdst, MdstE, flag, d_out);
}

// Round 14
// 140.664 us; speedup vs baseline: 1.2760x; 1.0318x over previous
//
#include <hip/hip_runtime.h>
#include <hip/hip_bf16.h>

#define B_    8
#define N_    2048
#define FIN_  256
#define FOUT_ 128
#define NROWS (B_*N_)

typedef __attribute__((ext_vector_type(8))) short short8;
typedef __attribute__((ext_vector_type(4))) float f32x4;

__device__ __forceinline__ float bf2f(unsigned short u) {
  return __uint_as_float(((unsigned int)u) << 16);
}
__device__ __forceinline__ unsigned short f2bf(float f) {
  unsigned int u = __float_as_uint(f);
  u += 0x7FFFu + ((u >> 16) & 1u);   // RNE
  return (unsigned short)(u >> 16);
}
__device__ __forceinline__ float ldin(const void* p, size_t idx, int isbf) {
  if (isbf) return bf2f(((const unsigned short*)p)[idx]);
  return ((const float*)p)[idx];
}
__device__ __forceinline__ unsigned pk2bf(float a, float b) {
  return (unsigned)f2bf(a) | ((unsigned)f2bf(b) << 16);   // low = a (RNE)
}
// monotone float<->uint encoding for atomicMax float-max (all finite enc > 0)
__device__ __forceinline__ unsigned encf(float f) {
  unsigned u = __float_as_uint(f);
  return (u & 0x80000000u) ? ~u : (u | 0x80000000u);
}
__device__ __forceinline__ float decf(unsigned k) {
  return (k & 0x80000000u) ? __uint_as_float(k ^ 0x80000000u) : __uint_as_float(~k);
}
// per-block dtype self-detect (deterministic across blocks)
__device__ __forceinline__ int detect_bf(const void* x, int* cnt) {
  const unsigned short* u = (const unsigned short*)x;
  int c = 0;
  for (int i = threadIdx.x; i < 8192; i += 256) {
    unsigned short v = u[i];
    int e = (v >> 7) & 0xFF;
    if ((e >= 110 && e <= 145) || (v & 0x7FFF) == 0) c++;
  }
  cnt[threadIdx.x] = c;
  __syncthreads();
  for (int s = 128; s > 0; s >>= 1) {
    if (threadIdx.x < s) cnt[threadIdx.x] += cnt[threadIdx.x + s];
    __syncthreads();
  }
  return cnt[0] > 7373;   // 0.9 * 8192
}

// ---------- kernel 0: self-detect; blocks 0..127: WT; block 128: wa, flag,
//            MdstE init ----------
__global__ __launch_bounds__(256)
void k_prep(const void* __restrict__ x, const void* __restrict__ W,
            const void* __restrict__ a,
            unsigned short* __restrict__ WT, float* __restrict__ wa,
            int* __restrict__ flag, unsigned* __restrict__ MdstE) {
  __shared__ int cnt[256];
  const int isbf = detect_bf(x, cnt);
  if (blockIdx.x < 128) {
    int f = blockIdx.x, k = threadIdx.x;
    WT[f * 256 + k] = f2bf(ldin(W, (size_t)k * 128 + f, isbf));
  } else {
    __shared__ float as_s[256];
    int k = threadIdx.x;
    as_s[k] = ldin(a, k, isbf);
    __syncthreads();
    float s = 0.f, d = 0.f;
    for (int f = 0; f < 128; f++) {
      float w = ldin(W, (size_t)k * 128 + f, isbf);
      s += w * as_s[f];
      d += w * as_s[128 + f];
    }
    wa[k] = s;
    wa[256 + k] = d;
    if (k == 0) *flag = isbf;
    if (k < 8) MdstE[k * 32] = 0u;     // 0 < enc(f) for all finite f
  }
}

// ---------- kernel 1: h = x@W bf16 MFMA -> hT; fused fsrc/fdst = x@wa;
//            fused per-batch fdst max via 1 padded atomic per block ----------
__global__ __launch_bounds__(256)
void k_h(const void* __restrict__ x, const unsigned short* __restrict__ WT,
         const float* __restrict__ wa, const int* __restrict__ flag,
         unsigned short* __restrict__ hT, float* __restrict__ fsrc,
         float* __restrict__ fdst, unsigned* __restrict__ MdstE) {
  __shared__ __align__(16) unsigned short xs[32][264];
  __shared__ float wa_s[512];
  __shared__ float mxs[8];
  const int isbf = *flag;
  const int t    = threadIdx.x;
  const int row0 = blockIdx.x * 32;

  wa_s[t] = wa[t];
  wa_s[256 + t] = wa[256 + t];
  __syncthreads();

  const int c = t & 31;
  float sp[4], dp[4];
  if (isbf) {
    const unsigned short* xu = (const unsigned short*)x;
#pragma unroll
    for (int u = 0; u < 4; u++) {
      int r = u * 8 + (t >> 5);
      short8 sh = *(const short8*)&xu[(size_t)(row0 + r) * FIN_ + c * 8];
      *(short8*)&xs[r][c * 8] = sh;
      float s = 0.f, d = 0.f;
#pragma unroll
      for (int e = 0; e < 8; e++) {
        float xv = bf2f((unsigned short)sh[e]);
        s += xv * wa_s[c * 8 + e];
        d += xv * wa_s[256 + c * 8 + e];
      }
      sp[u] = s; dp[u] = d;
    }
  } else {
    const float* xf = (const float*)x;
#pragma unroll
    for (int u = 0; u < 4; u++) {
      int r = u * 8 + (t >> 5);
      float4 v0 = *(const float4*)&xf[(size_t)(row0 + r) * FIN_ + c * 8];
      float4 v1 = *(const float4*)&xf[(size_t)(row0 + r) * FIN_ + c * 8 + 4];
      float vv[8] = {v0.x, v0.y, v0.z, v0.w, v1.x, v1.y, v1.z, v1.w};
      short8 sh;
      float s = 0.f, d = 0.f;
#pragma unroll
      for (int e = 0; e < 8; e++) {
        sh[e] = (short)f2bf(vv[e]);
        s += vv[e] * wa_s[c * 8 + e];
        d += vv[e] * wa_s[256 + c * 8 + e];
      }
      *(short8*)&xs[r][c * 8] = sh;
      sp[u] = s; dp[u] = d;
    }
  }
#pragma unroll
  for (int off = 16; off >= 1; off >>= 1) {
#pragma unroll
    for (int u = 0; u < 4; u++) {
      sp[u] += __shfl_xor(sp[u], off, 64);
      dp[u] += __shfl_xor(dp[u], off, 64);
    }
  }
  if (c == 0) {
    float lm = -1e30f;
#pragma unroll
    for (int u = 0; u < 4; u++) {
      int r = u * 8 + (t >> 5);
      fsrc[row0 + r] = sp[u];
      fdst[row0 + r] = dp[u];
      lm = fmaxf(lm, dp[u]);
    }
    mxs[t >> 5] = lm;
  }
  __syncthreads();
  if (t == 0) {
    float m8 = mxs[0];
#pragma unroll
    for (int i = 1; i < 8; i++) m8 = fmaxf(m8, mxs[i]);
    atomicMax(&MdstE[(row0 >> 11) * 32], encf(m8));   // 64 atomics/line, padded
  }

  const int lane = t & 63, w = t >> 6;
  const int m = lane & 15, quad = lane >> 4;
  const int slab = w >> 1, fh = w & 1;

  f32x4 acc[4];
#pragma unroll
  for (int i = 0; i < 4; i++) acc[i] = (f32x4){0.f, 0.f, 0.f, 0.f};

#pragma unroll
  for (int ks = 0; ks < 8; ks++) {
    short8 ah = *(const short8*)&xs[slab * 16 + m][ks * 32 + quad * 8];
#pragma unroll
    for (int ft = 0; ft < 4; ft++) {
      int f = fh * 64 + ft * 16 + m;
      short8 bh = *(const short8*)&WT[(size_t)f * 256 + ks * 32 + quad * 8];
      acc[ft] = __builtin_amdgcn_mfma_f32_16x16x32_bf16(ah, bh, acc[ft], 0, 0, 0);
    }
  }

  size_t n0 = (size_t)blockIdx.x * 2 + slab;
  unsigned short* hblk = hT + n0 * (FOUT_ * 16);
#pragma unroll
  for (int ft = 0; ft < 4; ft++) {
    int f = fh * 64 + ft * 16 + m;
    *(uint2*)&hblk[f * 16 + quad * 4] = make_uint2(
        pk2bf(acc[ft][0], acc[ft][1]), pk2bf(acc[ft][2], acc[ft][3]));
  }
}

// ---------- kernel 2: single-pass gated attention, full j-range -------------
// Grid = B*(N/16) = 1024 blocks, 256 threads. Round-13 structure with three
// logit-path changes:
//  * native __expf (v_exp) instead of libm exp2f (r13's VALUBusy=64% was
//    mostly exp2f's overflow/denormal fixup code)
//  * gate on d2 < 46.0517 (== loc > 0.01) -- breaks the exp->cmp dep chain
//  * denominator via ones-column MFMA (numerator-consistent bf16 weights;
//    kills lacc adds, lred LDS reduce, final barrier + epilogue loop)
__global__ __launch_bounds__(256, 6)
void k_attn(const unsigned short* __restrict__ hT, const void* __restrict__ coord,
            const float* __restrict__ fsrc, const float* __restrict__ fdst,
            const unsigned* __restrict__ MdstE, const int* __restrict__ flag,
            void* __restrict__ out) {
  const int isbf = *flag;
  const int tid = threadIdx.x;
  const int b   = blockIdx.x >> 7;
  const int q0  = (blockIdx.x & 127) * 16;

  __shared__ __align__(16) float4 cjs[1024];            // 16 KB (cx,cy,cz,fdst)
  __shared__ __align__(16) unsigned short phi[2][16][136];

  const int qA   = tid & 15;
  const int jseg = tid >> 4;                            // 0..15, 8 j's each
  const size_t qglb = (size_t)b * N_ + q0 + qA;
  const float cq0 = ldin(coord, qglb * 3 + 0, isbf);
  const float cq1 = ldin(coord, qglb * 3 + 1, isbf);
  const float cq2 = ldin(coord, qglb * 3 + 2, isbf);
  const float fsq = fsrc[qglb];
  const float Bq  = fmaxf(0.f, fsq + decf(MdstE[b * 32]));

  const int lane = tid & 63, w = tid >> 6;
  const int m = lane & 15, quad = lane >> 4;
  f32x4 acc[2], accD;
  acc[0] = (f32x4){0.f, 0.f, 0.f, 0.f};
  acc[1] = (f32x4){0.f, 0.f, 0.f, 0.f};
  accD   = (f32x4){0.f, 0.f, 0.f, 0.f};
  const short8 bones = {(short)0x3F80, (short)0x3F80, (short)0x3F80, (short)0x3F80,
                        (short)0x3F80, (short)0x3F80, (short)0x3F80, (short)0x3F80};

  const unsigned short* hTb = hT + (size_t)b * (N_ * FOUT_);
  const int colA = (w * 2 + 0) * 16 + m;
  const int colB = (w * 2 + 1) * 16 + m;
  const int co   = (quad & 1) * 8;
  const int chq  = quad >> 1;

  // stage half 0 (j in [0,1024)) with all 256 threads
  for (int r = tid; r < 1024; r += 256) {
    size_t jg = (size_t)b * N_ + r;
    cjs[r] = make_float4(ldin(coord, jg * 3 + 0, isbf), ldin(coord, jg * 3 + 1, isbf),
                         ldin(coord, jg * 3 + 2, isbf), fdst[jg]);
  }
  // tile-0 B-fragments
  short8 bcur[8];
#pragma unroll
  for (int ks = 0; ks < 4; ks++) {
    size_t base = (size_t)(ks * 2 + chq) * (FOUT_ * 16) + co;
    bcur[ks * 2 + 0] = *(const short8*)&hTb[base + colA * 16];
    bcur[ks * 2 + 1] = *(const short8*)&hTb[base + colB * 16];
  }
  __syncthreads();

  for (int t = 0; t < 16; t++) {
    if (t == 8) {
      // all waves past barrier_7 (done reading half 0); restage half 1
      for (int r = tid; r < 1024; r += 256) {
        size_t jg = (size_t)b * N_ + 1024 + r;
        cjs[r] = make_float4(ldin(coord, jg * 3 + 0, isbf), ldin(coord, jg * 3 + 1, isbf),
                             ldin(coord, jg * 3 + 2, isbf), fdst[jg]);
      }
      __syncthreads();
    }
    const int buf = t & 1;

    // ---- logits: 8 j's -> packed bf16 -> one uint4 LDS store ----
    const int jbase = (t & 7) * 128 + jseg * 8;
    unsigned pk[4];
#pragma unroll
    for (int jp = 0; jp < 4; jp++) {
      float pv[2];
#pragma unroll
      for (int h = 0; h < 2; h++) {
        float4 cj = cjs[jbase + jp * 2 + h];
        float dx = cq0 - cj.x, dy = cq1 - cj.y, dz = cq2 - cj.z;
        float d2 = dx * dx + dy * dy + dz * dz;
        float loc = __expf(-0.1f * d2);
        float e = fsq + cj.w;
        e = fmaxf(e, 0.2f * e);                       // leaky relu
        float p = (d2 < 46.0517f) ? __expf(fmaf(e, loc, -Bq)) : 0.f;
        pv[h] = p;
      }
      pk[jp] = pk2bf(pv[0], pv[1]);
    }
    *(uint4*)&phi[buf][qA][jseg * 8] = make_uint4(pk[0], pk[1], pk[2], pk[3]);
    __syncthreads();   // one barrier per 128-j tile

    // ---- PV MFMA: 4 k-steps of 32, 2 f-tiles + ones-column denominator ----
#pragma unroll
    for (int ks = 0; ks < 4; ks++) {
      short8 ah = *(const short8*)&phi[buf][m][ks * 32 + quad * 8];
      acc[0] = __builtin_amdgcn_mfma_f32_16x16x32_bf16(ah, bcur[ks * 2 + 0], acc[0], 0, 0, 0);
      acc[1] = __builtin_amdgcn_mfma_f32_16x16x32_bf16(ah, bcur[ks * 2 + 1], acc[1], 0, 0, 0);
      accD   = __builtin_amdgcn_mfma_f32_16x16x32_bf16(ah, bones, accD, 0, 0, 0);
    }
    // reload B-fragments for tile t+1 (covered by next logit phase + barrier)
    if (t < 15) {
      const int jcb = (t + 1) * 8;
#pragma unroll
      for (int ks = 0; ks < 4; ks++) {
        size_t base = (size_t)(jcb + ks * 2 + chq) * (FOUT_ * 16) + co;
        bcur[ks * 2 + 0] = *(const short8*)&hTb[base + colA * 16];
        bcur[ks * 2 + 1] = *(const short8*)&hTb[base + colB * 16];
      }
    }
  }

  // ---- normalize, elu, store (D: row q = quad*4+r, col f); accD[r] holds
  //      the full denominator for row q (every column equal) ----
#pragma unroll
  for (int f2 = 0; f2 < 2; f2++) {
    int f = (w * 2 + f2) * 16 + m;
#pragma unroll
    for (int r = 0; r < 4; r++) {
      int q = quad * 4 + r;
      float v = acc[f2][r] / fmaxf(accD[r], 1e-30f);
      v = (v > 0.f) ? v : expm1f(v);
      size_t oidx = ((size_t)(b * N_ + q0 + q)) * FOUT_ + f;
      if (isbf) ((unsigned short*)out)[oidx] = f2bf(v);
      else      ((float*)out)[oidx] = v;
    }
  }
}

extern "C" void kernel_launch(void* const* d_in, const int* in_sizes, int n_in,
                              void* d_out, int out_size, void* d_ws, size_t ws_size,
                              hipStream_t stream) {
  const void* x     = d_in[0];
  const void* coord = d_in[1];
  const void* W     = d_in[2];
  const void* a     = d_in[3];

  // ws: [512-float header: flag@0, MdstE @ uint 64 (stride 32)]
  //     [hT][WT][wa][fsrc][fdst]
  int*            flag  = (int*)d_ws;
  unsigned*       MdstE = (unsigned*)d_ws + 64;
  unsigned short* hT    = (unsigned short*)((float*)d_ws + 512);
  unsigned short* WT    = hT + (size_t)NROWS * FOUT_;
  float*          wa    = (float*)(WT + 128 * 256);
  float*          fsrc  = wa + 512;
  float*          fdst  = fsrc + NROWS;

  k_prep<<<129, 256, 0, stream>>>(x, W, a, WT, wa, flag, MdstE);
  k_h   <<<NROWS / 32, 256, 0, stream>>>(x, WT, wa, flag, hT, fsrc, fdst, MdstE);
  k_attn<<<B_ * (N_ / 16), 256, 0, stream>>>(hT, coord, fsrc, fdst, MdstE, flag, d_out);
}